// Round 1
// baseline (2960.265 us; speedup 1.0000x reference)
//
#include <hip/hip_runtime.h>

#define N_NODES 50000
#define N_EDGES 800000
#define D_IN    512
#define D_OUT   256

// ---------------- degree kernels ----------------
__global__ void k_deg_init(float* __restrict__ deg) {
    int i = blockIdx.x * 256 + threadIdx.x;
    if (i < N_NODES) deg[i] = 1.0f;   // self-loop contribution
}

__global__ void k_deg_count(const int* __restrict__ col, float* __restrict__ deg) {
    int i = blockIdx.x * 256 + threadIdx.x;
    if (i < N_EDGES) atomicAdd(&deg[col[i]], 1.0f);
}

__global__ void k_dinv(float* __restrict__ deg) {
    int i = blockIdx.x * 256 + threadIdx.x;
    if (i < N_NODES) deg[i] = rsqrtf(deg[i]);   // deg >= 1 always
}

// ---------------- GEMM: y = (x @ W) * dinv[row]; also writes d_out = y ----------------
// BM=64, BN=256 (full width), BK=16. 256 threads, 8x8 micro-tile per thread.
#define BM 64
#define BK 16
__launch_bounds__(256)
__global__ void k_gemm(const float* __restrict__ A,      // [N_NODES, D_IN]
                       const float* __restrict__ B,      // [D_IN, D_OUT]
                       const float* __restrict__ dinv,   // [N_NODES]
                       float* __restrict__ y,            // [N_NODES, D_OUT]
                       float* __restrict__ out)          // [N_NODES, D_OUT]
{
    __shared__ float As[BK][BM];      // 4 KB
    __shared__ float Bs[BK][D_OUT];   // 16 KB

    const int m0 = blockIdx.x * BM;
    const int t  = threadIdx.x;
    const int tr = t >> 5;      // 0..7  -> rows tr*8 + i
    const int tc = t & 31;      // 0..31 -> cols tc + 32*j

    // A staging map: thread t loads A[m0 + t/4][kk + (t%4)*4 .. +3]
    const int la_m = t >> 2;
    const int la_k = (t & 3) * 4;
    // B staging map: thread t loads B[kk + t/16][(t%16)*16 + 4q .. ]
    const int lb_k = t >> 4;
    const int lb_n = (t & 15) * 16;

    float acc[8][8];
    #pragma unroll
    for (int i = 0; i < 8; ++i)
        #pragma unroll
        for (int j = 0; j < 8; ++j) acc[i][j] = 0.0f;

    for (int kk = 0; kk < D_IN; kk += BK) {
        // stage A (with tail guard on M)
        float4 av = make_float4(0.f, 0.f, 0.f, 0.f);
        if (m0 + la_m < N_NODES)
            av = *(const float4*)&A[(size_t)(m0 + la_m) * D_IN + kk + la_k];
        As[la_k + 0][la_m] = av.x;
        As[la_k + 1][la_m] = av.y;
        As[la_k + 2][la_m] = av.z;
        As[la_k + 3][la_m] = av.w;
        // stage B
        #pragma unroll
        for (int q = 0; q < 4; ++q) {
            float4 bv = *(const float4*)&B[(size_t)(kk + lb_k) * D_OUT + lb_n + 4 * q];
            *(float4*)&Bs[lb_k][lb_n + 4 * q] = bv;
        }
        __syncthreads();

        #pragma unroll
        for (int k = 0; k < BK; ++k) {
            float a[8], b[8];
            *(float4*)&a[0] = *(const float4*)&As[k][tr * 8];
            *(float4*)&a[4] = *(const float4*)&As[k][tr * 8 + 4];
            #pragma unroll
            for (int j = 0; j < 8; ++j) b[j] = Bs[k][tc + 32 * j];
            #pragma unroll
            for (int i = 0; i < 8; ++i)
                #pragma unroll
                for (int j = 0; j < 8; ++j)
                    acc[i][j] = fmaf(a[i], b[j], acc[i][j]);
        }
        __syncthreads();
    }

    // epilogue: scale by dinv[m], write y and self-loop init of out
    #pragma unroll
    for (int i = 0; i < 8; ++i) {
        int m = m0 + tr * 8 + i;
        if (m < N_NODES) {
            float s = dinv[m];
            #pragma unroll
            for (int j = 0; j < 8; ++j) {
                float v = acc[i][j] * s;
                int n = tc + 32 * j;
                y[(size_t)m * D_OUT + n]   = v;
                out[(size_t)m * D_OUT + n] = v;
            }
        }
    }
}

// ---------------- edge scatter: out[col] += y[row] ----------------
// one wave (64 lanes) per edge; lane handles 4 contiguous floats
__launch_bounds__(256)
__global__ void k_scatter(const int* __restrict__ row, const int* __restrict__ col,
                          const float* __restrict__ y, float* __restrict__ out)
{
    int e    = (blockIdx.x * 256 + threadIdx.x) >> 6;
    int lane = threadIdx.x & 63;
    if (e >= N_EDGES) return;
    int r = __builtin_amdgcn_readfirstlane(row[e]);
    int c = __builtin_amdgcn_readfirstlane(col[e]);
    float4 v = *(const float4*)&y[(size_t)r * D_OUT + lane * 4];
    float* dst = &out[(size_t)c * D_OUT + lane * 4];
    atomicAdd(dst + 0, v.x);
    atomicAdd(dst + 1, v.y);
    atomicAdd(dst + 2, v.z);
    atomicAdd(dst + 3, v.w);
}

// ---------------- finish: out = relu(dinv[node]*out + b) ----------------
__launch_bounds__(256)
__global__ void k_finish(float* __restrict__ out, const float* __restrict__ dinv,
                         const float* __restrict__ bias)
{
    int idx = blockIdx.x * 256 + threadIdx.x;        // one float4 per thread
    const int tot = N_NODES * D_OUT / 4;             // 3,200,000
    if (idx >= tot) return;
    int node = idx >> 6;        // 64 float4 per row
    int q    = idx & 63;
    float s = dinv[node];
    float4 v  = ((float4*)out)[idx];
    float4 bb = ((const float4*)bias)[q];
    v.x = fmaxf(fmaf(v.x, s, bb.x), 0.0f);
    v.y = fmaxf(fmaf(v.y, s, bb.y), 0.0f);
    v.z = fmaxf(fmaf(v.z, s, bb.z), 0.0f);
    v.w = fmaxf(fmaf(v.w, s, bb.w), 0.0f);
    ((float4*)out)[idx] = v;
}

extern "C" void kernel_launch(void* const* d_in, const int* in_sizes, int n_in,
                              void* d_out, int out_size, void* d_ws, size_t ws_size,
                              hipStream_t stream) {
    const float* x   = (const float*)d_in[0];
    const int*   ei  = (const int*)d_in[1];     // [2, N_EDGES] int32
    const float* W   = (const float*)d_in[2];
    const float* b   = (const float*)d_in[3];
    float*       out = (float*)d_out;

    const int* row = ei;             // sources
    const int* col = ei + N_EDGES;   // targets

    // workspace: y [N_NODES*D_OUT f32] | deg/dinv [N_NODES f32]
    float* y    = (float*)d_ws;
    float* dinv = (float*)((char*)d_ws + (size_t)N_NODES * D_OUT * sizeof(float));

    k_deg_init <<<(N_NODES + 255) / 256, 256, 0, stream>>>(dinv);
    k_deg_count<<<(N_EDGES + 255) / 256, 256, 0, stream>>>(col, dinv);
    k_dinv     <<<(N_NODES + 255) / 256, 256, 0, stream>>>(dinv);

    k_gemm<<<(N_NODES + BM - 1) / BM, 256, 0, stream>>>(x, W, dinv, y, out);

    k_scatter<<<(N_EDGES * 64 + 255) / 256, 256, 0, stream>>>(row, col, y, out);

    k_finish<<<(N_NODES * D_OUT / 4 + 255) / 256, 256, 0, stream>>>(out, dinv, b);
}

// Round 2
// 521.448 us; speedup vs baseline: 5.6770x; 5.6770x over previous
//
#include <hip/hip_runtime.h>

#define N_NODES 50000
#define N_EDGES 800000
#define D_IN    512
#define D_OUT   256

// ============ CSR build ============

__global__ void k_count(const int* __restrict__ col, int* __restrict__ cnt) {
    int i = blockIdx.x * 256 + threadIdx.x;
    if (i < N_EDGES) atomicAdd(&cnt[col[i]], 1);
}

// single-block exclusive scan of cnt[0..N_NODES) -> row_ptr[0..N_NODES]
#define SCAN_T 1024
__launch_bounds__(SCAN_T)
__global__ void k_scan(const int* __restrict__ cnt, int* __restrict__ row_ptr) {
    __shared__ int sums[SCAN_T];
    const int t   = threadIdx.x;
    const int per = (N_NODES + SCAN_T - 1) / SCAN_T;   // 49
    const int base = t * per;
    int s = 0;
    for (int i = 0; i < per; ++i) {
        int idx = base + i;
        if (idx < N_NODES) s += cnt[idx];
    }
    sums[t] = s;
    __syncthreads();
    // Hillis-Steele inclusive scan over 1024 partials
    for (int off = 1; off < SCAN_T; off <<= 1) {
        int v = (t >= off) ? sums[t - off] : 0;
        __syncthreads();
        sums[t] += v;
        __syncthreads();
    }
    int run = (t == 0) ? 0 : sums[t - 1];   // exclusive prefix of my chunk
    for (int i = 0; i < per; ++i) {
        int idx = base + i;
        if (idx < N_NODES) {
            row_ptr[idx] = run;
            run += cnt[idx];
        }
    }
    if (t == 0) row_ptr[N_NODES] = sums[SCAN_T - 1];
}

__global__ void k_prep(const int* __restrict__ cnt, const int* __restrict__ row_ptr,
                       float* __restrict__ dinv, int* __restrict__ cursor) {
    int i = blockIdx.x * 256 + threadIdx.x;
    if (i < N_NODES) {
        dinv[i]   = rsqrtf(1.0f + (float)cnt[i]);   // deg incl. self-loop
        cursor[i] = row_ptr[i];
    }
}

__global__ void k_fill(const int* __restrict__ row, const int* __restrict__ col,
                       int* __restrict__ cursor, int* __restrict__ csr_src) {
    int i = blockIdx.x * 256 + threadIdx.x;
    if (i < N_EDGES) {
        int pos = atomicAdd(&cursor[col[i]], 1);
        csr_src[pos] = row[i];
    }
}

// ============ GEMM: y = (x @ W) * dinv[row] ============
// BM=64, BN=256 (full width), BK=16. 256 threads, 8x8 micro-tile per thread.
#define BM 64
#define BK 16
__launch_bounds__(256)
__global__ void k_gemm(const float* __restrict__ A,      // [N_NODES, D_IN]
                       const float* __restrict__ B,      // [D_IN, D_OUT]
                       const float* __restrict__ dinv,   // [N_NODES]
                       float* __restrict__ y)            // [N_NODES, D_OUT]
{
    __shared__ float As[BK][BM];      // 4 KB
    __shared__ float Bs[BK][D_OUT];   // 16 KB

    const int m0 = blockIdx.x * BM;
    const int t  = threadIdx.x;
    const int tr = t >> 5;      // 0..7  -> rows tr*8 + i
    const int tc = t & 31;      // 0..31 -> cols tc + 32*j

    const int la_m = t >> 2;
    const int la_k = (t & 3) * 4;
    const int lb_k = t >> 4;
    const int lb_n = (t & 15) * 16;

    float acc[8][8];
    #pragma unroll
    for (int i = 0; i < 8; ++i)
        #pragma unroll
        for (int j = 0; j < 8; ++j) acc[i][j] = 0.0f;

    for (int kk = 0; kk < D_IN; kk += BK) {
        float4 av = make_float4(0.f, 0.f, 0.f, 0.f);
        if (m0 + la_m < N_NODES)
            av = *(const float4*)&A[(size_t)(m0 + la_m) * D_IN + kk + la_k];
        As[la_k + 0][la_m] = av.x;
        As[la_k + 1][la_m] = av.y;
        As[la_k + 2][la_m] = av.z;
        As[la_k + 3][la_m] = av.w;
        #pragma unroll
        for (int q = 0; q < 4; ++q) {
            float4 bv = *(const float4*)&B[(size_t)(kk + lb_k) * D_OUT + lb_n + 4 * q];
            *(float4*)&Bs[lb_k][lb_n + 4 * q] = bv;
        }
        __syncthreads();

        #pragma unroll
        for (int k = 0; k < BK; ++k) {
            float a[8], b[8];
            *(float4*)&a[0] = *(const float4*)&As[k][tr * 8];
            *(float4*)&a[4] = *(const float4*)&As[k][tr * 8 + 4];
            #pragma unroll
            for (int j = 0; j < 8; ++j) b[j] = Bs[k][tc + 32 * j];
            #pragma unroll
            for (int i = 0; i < 8; ++i)
                #pragma unroll
                for (int j = 0; j < 8; ++j)
                    acc[i][j] = fmaf(a[i], b[j], acc[i][j]);
        }
        __syncthreads();
    }

    #pragma unroll
    for (int i = 0; i < 8; ++i) {
        int m = m0 + tr * 8 + i;
        if (m < N_NODES) {
            float s = dinv[m];
            #pragma unroll
            for (int j = 0; j < 8; ++j)
                y[(size_t)m * D_OUT + tc + 32 * j] = acc[i][j] * s;
        }
    }
}

// ============ gather: out[c] = relu(dinv[c]*(y[c] + sum y[src]) + b) ============
// one 64-lane block per target node; lane owns 4 contiguous output columns
__launch_bounds__(64)
__global__ void k_gather(const int* __restrict__ row_ptr, const int* __restrict__ csr_src,
                         const float* __restrict__ y, const float* __restrict__ dinv,
                         const float* __restrict__ bias, float* __restrict__ out)
{
    const int c    = blockIdx.x;
    const int lane = threadIdx.x;
    const float4* y4 = (const float4*)y;

    float4 acc = y4[(size_t)c * 64 + lane];   // self-loop term
    const int s = row_ptr[c];
    const int e = row_ptr[c + 1];

    int i = s;
    for (; i + 4 <= e; i += 4) {
        int r0 = csr_src[i + 0];
        int r1 = csr_src[i + 1];
        int r2 = csr_src[i + 2];
        int r3 = csr_src[i + 3];
        float4 v0 = y4[(size_t)r0 * 64 + lane];
        float4 v1 = y4[(size_t)r1 * 64 + lane];
        float4 v2 = y4[(size_t)r2 * 64 + lane];
        float4 v3 = y4[(size_t)r3 * 64 + lane];
        acc.x += (v0.x + v1.x) + (v2.x + v3.x);
        acc.y += (v0.y + v1.y) + (v2.y + v3.y);
        acc.z += (v0.z + v1.z) + (v2.z + v3.z);
        acc.w += (v0.w + v1.w) + (v2.w + v3.w);
    }
    for (; i < e; ++i) {
        int r = csr_src[i];
        float4 v = y4[(size_t)r * 64 + lane];
        acc.x += v.x; acc.y += v.y; acc.z += v.z; acc.w += v.w;
    }

    const float sc = dinv[c];
    float4 bb = ((const float4*)bias)[lane];
    float4 o;
    o.x = fmaxf(fmaf(acc.x, sc, bb.x), 0.0f);
    o.y = fmaxf(fmaf(acc.y, sc, bb.y), 0.0f);
    o.z = fmaxf(fmaf(acc.z, sc, bb.z), 0.0f);
    o.w = fmaxf(fmaf(acc.w, sc, bb.w), 0.0f);
    ((float4*)out)[(size_t)c * 64 + lane] = o;
}

extern "C" void kernel_launch(void* const* d_in, const int* in_sizes, int n_in,
                              void* d_out, int out_size, void* d_ws, size_t ws_size,
                              hipStream_t stream) {
    const float* x   = (const float*)d_in[0];
    const int*   ei  = (const int*)d_in[1];     // [2, N_EDGES] int32
    const float* W   = (const float*)d_in[2];
    const float* b   = (const float*)d_in[3];
    float*       out = (float*)d_out;

    const int* row = ei;             // sources
    const int* col = ei + N_EDGES;   // targets

    // workspace layout
    char* p = (char*)d_ws;
    float* y       = (float*)p;                 p += (size_t)N_NODES * D_OUT * sizeof(float); // 51.2 MB
    int*   csr_src = (int*)p;                   p += (size_t)N_EDGES * sizeof(int);           // 3.2 MB
    int*   cnt     = (int*)p;                   p += (size_t)N_NODES * sizeof(int);
    int*   row_ptr = (int*)p;                   p += (size_t)(N_NODES + 1) * sizeof(int);
    int*   cursor  = (int*)p;                   p += (size_t)N_NODES * sizeof(int);
    float* dinv    = (float*)p;                 p += (size_t)N_NODES * sizeof(float);

    hipMemsetAsync(cnt, 0, (size_t)N_NODES * sizeof(int), stream);
    k_count<<<(N_EDGES + 255) / 256, 256, 0, stream>>>(col, cnt);
    k_scan <<<1, SCAN_T, 0, stream>>>(cnt, row_ptr);
    k_prep <<<(N_NODES + 255) / 256, 256, 0, stream>>>(cnt, row_ptr, dinv, cursor);
    k_fill <<<(N_EDGES + 255) / 256, 256, 0, stream>>>(row, col, cursor, csr_src);

    k_gemm<<<(N_NODES + BM - 1) / BM, 256, 0, stream>>>(x, W, dinv, y);

    k_gather<<<N_NODES, 64, 0, stream>>>(row_ptr, csr_src, y, dinv, b, out);
}

// Round 3
// 310.134 us; speedup vs baseline: 9.5451x; 1.6814x over previous
//
#include <hip/hip_runtime.h>
#include <hip/hip_bf16.h>

#define N_NODES 50000
#define N_EDGES 800000
#define D_IN    512
#define D_OUT   256

typedef short s8v  __attribute__((ext_vector_type(8)));
typedef float f32x4 __attribute__((ext_vector_type(4)));

__device__ __forceinline__ unsigned short bf16b(float f) {
    __hip_bfloat16 h = __float2bfloat16(f);   // RNE; compiler fuses pairs to v_cvt_pk_bf16_f32
    return *reinterpret_cast<unsigned short*>(&h);
}

// ============ CSR build ============

__global__ void k_count(const int* __restrict__ col, int* __restrict__ cnt) {
    int i = blockIdx.x * 256 + threadIdx.x;
    if (i < N_EDGES) atomicAdd(&cnt[col[i]], 1);
}

#define SCAN_T 1024
__launch_bounds__(SCAN_T)
__global__ void k_scan(const int* __restrict__ cnt, int* __restrict__ row_ptr) {
    __shared__ int sums[SCAN_T];
    const int t   = threadIdx.x;
    const int per = (N_NODES + SCAN_T - 1) / SCAN_T;   // 49
    const int base = t * per;
    int s = 0;
    for (int i = 0; i < per; ++i) {
        int idx = base + i;
        if (idx < N_NODES) s += cnt[idx];
    }
    sums[t] = s;
    __syncthreads();
    for (int off = 1; off < SCAN_T; off <<= 1) {
        int v = (t >= off) ? sums[t - off] : 0;
        __syncthreads();
        sums[t] += v;
        __syncthreads();
    }
    int run = (t == 0) ? 0 : sums[t - 1];
    for (int i = 0; i < per; ++i) {
        int idx = base + i;
        if (idx < N_NODES) {
            row_ptr[idx] = run;
            run += cnt[idx];
        }
    }
    if (t == 0) row_ptr[N_NODES] = sums[SCAN_T - 1];
}

__global__ void k_prep(const int* __restrict__ cnt, const int* __restrict__ row_ptr,
                       float* __restrict__ dinv, int* __restrict__ cursor) {
    int i = blockIdx.x * 256 + threadIdx.x;
    if (i < N_NODES) {
        dinv[i]   = rsqrtf(1.0f + (float)cnt[i]);
        cursor[i] = row_ptr[i];
    }
}

__global__ void k_fill(const int* __restrict__ row, const int* __restrict__ col,
                       int* __restrict__ cursor, int* __restrict__ csr_src) {
    int i = blockIdx.x * 256 + threadIdx.x;
    if (i < N_EDGES) {
        int pos = atomicAdd(&cursor[col[i]], 1);
        csr_src[pos] = row[i];
    }
}

// ============ W transpose + bf16 convert: Wt[n][k] = bf16(W[k][n]) ============
__global__ void k_wt(const float* __restrict__ W, unsigned short* __restrict__ Wt) {
    int k = blockIdx.x;      // 512
    int n = threadIdx.x;     // 256
    Wt[(size_t)n * D_IN + k] = bf16b(W[(size_t)k * D_OUT + n]);
}

// ============ MFMA GEMM: yb = bf16((x @ W) * dinv[row]) ============
// 128x128 tile, BK=64, 4 waves (2x2), 16x16x32 bf16 MFMA, XOR-swizzled LDS.
__launch_bounds__(256)
__global__ void k_gemm(const float* __restrict__ A,            // [N_NODES, 512] fp32
                       const unsigned short* __restrict__ Wt,  // [256, 512] bf16
                       const float* __restrict__ dinv,
                       unsigned short* __restrict__ yb)        // [N_NODES, 256] bf16
{
    __shared__ __align__(16) unsigned short As[128 * 64];   // [m][k], swizzled
    __shared__ __align__(16) unsigned short Bs[128 * 64];   // [n][k], swizzled

    const int t  = threadIdx.x;
    const int nt = blockIdx.x & 1;
    const int mt = blockIdx.x >> 1;
    const int m0 = mt * 128;
    const int n0 = nt * 128;

    const int w  = t >> 6;
    const int l  = t & 63;
    const int wm = (w >> 1) * 64;
    const int wn = (w & 1) * 64;
    const int lr = l & 15;
    const int lk = l >> 4;

    // staging map: thread covers rows {i*32 + t>>3}, k-group t&7 (8 elems)
    const int sr   = t >> 3;
    const int skg  = t & 7;
    const int swz  = (sr & 7) << 4;        // row-XOR swizzle (rows ≡ sr mod 8)
    const int aswz = (lr & 7) << 4;        // frag-read swizzle (m%8 == lr%8)

    f32x4 acc[4][4] = {};

    for (int kk = 0; kk < D_IN; kk += 64) {
        #pragma unroll
        for (int i = 0; i < 4; ++i) {
            int m   = i * 32 + sr;
            int row = m0 + m;
            float4 v0 = make_float4(0.f,0.f,0.f,0.f), v1 = v0;
            if (row < N_NODES) {
                const float* src = &A[(size_t)row * D_IN + kk + skg * 8];
                v0 = *(const float4*)src;
                v1 = *(const float4*)(src + 4);
            }
            union { uint4 q; unsigned short h[8]; } pk;
            pk.h[0] = bf16b(v0.x); pk.h[1] = bf16b(v0.y);
            pk.h[2] = bf16b(v0.z); pk.h[3] = bf16b(v0.w);
            pk.h[4] = bf16b(v1.x); pk.h[5] = bf16b(v1.y);
            pk.h[6] = bf16b(v1.z); pk.h[7] = bf16b(v1.w);
            *(uint4*)((char*)As + ((m * 128 + skg * 16) ^ swz)) = pk.q;
        }
        #pragma unroll
        for (int i = 0; i < 4; ++i) {
            int n = i * 32 + sr;
            uint4 q = *(const uint4*)&Wt[(size_t)(n0 + n) * D_IN + kk + skg * 8];
            *(uint4*)((char*)Bs + ((n * 128 + skg * 16) ^ swz)) = q;
        }
        __syncthreads();

        #pragma unroll
        for (int ks = 0; ks < 2; ++ks) {
            const int kb = (ks * 64 + lk * 16) ^ aswz;
            s8v af[4], bfr[4];
            #pragma unroll
            for (int f = 0; f < 4; ++f)
                af[f]  = *(const s8v*)((const char*)As + ((wm + f * 16 + lr) * 128 + kb));
            #pragma unroll
            for (int f = 0; f < 4; ++f)
                bfr[f] = *(const s8v*)((const char*)Bs + ((wn + f * 16 + lr) * 128 + kb));
            #pragma unroll
            for (int fm = 0; fm < 4; ++fm)
                #pragma unroll
                for (int fn = 0; fn < 4; ++fn)
                    acc[fm][fn] = __builtin_amdgcn_mfma_f32_16x16x32_bf16(
                        af[fm], bfr[fn], acc[fm][fn], 0, 0, 0);
        }
        __syncthreads();
    }

    // epilogue: C/D layout col=lane&15, row=(lane>>4)*4+j
    #pragma unroll
    for (int fm = 0; fm < 4; ++fm) {
        #pragma unroll
        for (int j = 0; j < 4; ++j) {
            int row = m0 + wm + fm * 16 + lk * 4 + j;
            if (row < N_NODES) {
                float s = dinv[row];
                #pragma unroll
                for (int fn = 0; fn < 4; ++fn) {
                    int col = n0 + wn + fn * 16 + lr;
                    yb[(size_t)row * D_OUT + col] = bf16b(acc[fm][fn][j] * s);
                }
            }
        }
    }
}

// ============ gather: out[c] = relu(dinv[c]*(yb[c] + sum yb[src]) + b) ============
// 256 threads = 4 waves = 4 nodes/block. Per wave: 2 edge-groups x 32 col-slots.
__device__ __forceinline__ void add8(float* acc, uint4 q) {
    unsigned x;
    x = q.x; acc[0] += __uint_as_float(x << 16); acc[1] += __uint_as_float(x & 0xffff0000u);
    x = q.y; acc[2] += __uint_as_float(x << 16); acc[3] += __uint_as_float(x & 0xffff0000u);
    x = q.z; acc[4] += __uint_as_float(x << 16); acc[5] += __uint_as_float(x & 0xffff0000u);
    x = q.w; acc[6] += __uint_as_float(x << 16); acc[7] += __uint_as_float(x & 0xffff0000u);
}

__launch_bounds__(256)
__global__ void k_gather(const int* __restrict__ row_ptr, const int* __restrict__ csr_src,
                         const unsigned short* __restrict__ yb, const float* __restrict__ dinv,
                         const float* __restrict__ bias, float* __restrict__ out)
{
    const int c  = blockIdx.x * 4 + (threadIdx.x >> 6);
    const int l  = threadIdx.x & 63;
    const int eg = l >> 5;              // edge-group 0/1
    const int cs = l & 31;              // col-slot: cols cs*8 .. cs*8+7
    const size_t colb = (size_t)cs * 8;

    float acc[8] = {0.f,0.f,0.f,0.f,0.f,0.f,0.f,0.f};

    const int s = row_ptr[c];
    const int e = row_ptr[c + 1];

    int i = s + eg;
    while (i + 14 < e) {                // 8 edges per half in flight
        int r[8];
        #pragma unroll
        for (int u = 0; u < 8; ++u) r[u] = csr_src[i + 2 * u];
        uint4 v[8];
        #pragma unroll
        for (int u = 0; u < 8; ++u) v[u] = *(const uint4*)&yb[(size_t)r[u] * D_OUT + colb];
        #pragma unroll
        for (int u = 0; u < 8; ++u) add8(acc, v[u]);
        i += 16;
    }
    if (i + 6 < e) {                    // 4-edge step
        int r[4];
        #pragma unroll
        for (int u = 0; u < 4; ++u) r[u] = csr_src[i + 2 * u];
        uint4 v[4];
        #pragma unroll
        for (int u = 0; u < 4; ++u) v[u] = *(const uint4*)&yb[(size_t)r[u] * D_OUT + colb];
        #pragma unroll
        for (int u = 0; u < 4; ++u) add8(acc, v[u]);
        i += 8;
    }
    while (i < e) {
        int r = csr_src[i];
        uint4 v = *(const uint4*)&yb[(size_t)r * D_OUT + colb];
        add8(acc, v);
        i += 2;
    }

    // combine the two edge-group halves
    #pragma unroll
    for (int u = 0; u < 8; ++u) acc[u] += __shfl_xor(acc[u], 32, 64);

    // self-loop term
    uint4 sv = *(const uint4*)&yb[(size_t)c * D_OUT + colb];
    add8(acc, sv);

    if (eg == 0) {
        const float sc = dinv[c];
        float4 b0 = *(const float4*)&bias[colb];
        float4 b1 = *(const float4*)&bias[colb + 4];
        float4 o0, o1;
        o0.x = fmaxf(fmaf(acc[0], sc, b0.x), 0.f);
        o0.y = fmaxf(fmaf(acc[1], sc, b0.y), 0.f);
        o0.z = fmaxf(fmaf(acc[2], sc, b0.z), 0.f);
        o0.w = fmaxf(fmaf(acc[3], sc, b0.w), 0.f);
        o1.x = fmaxf(fmaf(acc[4], sc, b1.x), 0.f);
        o1.y = fmaxf(fmaf(acc[5], sc, b1.y), 0.f);
        o1.z = fmaxf(fmaf(acc[6], sc, b1.z), 0.f);
        o1.w = fmaxf(fmaf(acc[7], sc, b1.w), 0.f);
        float* dst = &out[(size_t)c * D_OUT + colb];
        *(float4*)dst       = o0;
        *(float4*)(dst + 4) = o1;
    }
}

extern "C" void kernel_launch(void* const* d_in, const int* in_sizes, int n_in,
                              void* d_out, int out_size, void* d_ws, size_t ws_size,
                              hipStream_t stream) {
    const float* x   = (const float*)d_in[0];
    const int*   ei  = (const int*)d_in[1];
    const float* W   = (const float*)d_in[2];
    const float* b   = (const float*)d_in[3];
    float*       out = (float*)d_out;

    const int* row = ei;
    const int* col = ei + N_EDGES;

    char* p = (char*)d_ws;
    unsigned short* yb = (unsigned short*)p;  p += (size_t)N_NODES * D_OUT * 2;   // 25.6 MB
    unsigned short* Wt = (unsigned short*)p;  p += (size_t)D_OUT * D_IN * 2;      // 256 KB
    int*   csr_src = (int*)p;                 p += (size_t)N_EDGES * 4;           // 3.2 MB
    int*   cnt     = (int*)p;                 p += (size_t)N_NODES * 4;
    int*   row_ptr = (int*)p;                 p += (size_t)(N_NODES + 1) * 4;
    int*   cursor  = (int*)p;                 p += (size_t)N_NODES * 4;
    float* dinv    = (float*)p;               p += (size_t)N_NODES * 4;

    hipMemsetAsync(cnt, 0, (size_t)N_NODES * sizeof(int), stream);
    k_count<<<(N_EDGES + 255) / 256, 256, 0, stream>>>(col, cnt);
    k_scan <<<1, SCAN_T, 0, stream>>>(cnt, row_ptr);
    k_prep <<<(N_NODES + 255) / 256, 256, 0, stream>>>(cnt, row_ptr, dinv, cursor);
    k_fill <<<(N_EDGES + 255) / 256, 256, 0, stream>>>(row, col, cursor, csr_src);
    k_wt   <<<D_IN, D_OUT, 0, stream>>>(W, Wt);

    k_gemm<<<((N_NODES + 127) / 128) * 2, 256, 0, stream>>>(x, Wt, dinv, yb);

    k_gather<<<N_NODES / 4, 256, 0, stream>>>(row_ptr, csr_src, yb, dinv, b, out);
}

// Round 4
// 228.223 us; speedup vs baseline: 12.9710x; 1.3589x over previous
//
#include <hip/hip_runtime.h>
#include <hip/hip_bf16.h>

#define N_NODES 50000
#define N_EDGES 800000
#define D_IN    512
#define D_OUT   256
#define NBLK_SCAN ((N_NODES + 1023) / 1024)   // 49

typedef short s8v  __attribute__((ext_vector_type(8)));
typedef float f32x4 __attribute__((ext_vector_type(4)));

__device__ __forceinline__ unsigned short bf16b(float f) {
    __hip_bfloat16 h = __float2bfloat16(f);
    return *reinterpret_cast<unsigned short*>(&h);
}

__device__ __forceinline__ int wave_incl_scan(int v, int lane) {
    #pragma unroll
    for (int d = 1; d < 64; d <<= 1) {
        int u = __shfl_up(v, d, 64);
        if (lane >= d) v += u;
    }
    return v;
}

// ============ CSR build ============

__global__ void k_count(const int* __restrict__ col, int* __restrict__ cnt) {
    int i = blockIdx.x * 256 + threadIdx.x;
    if (i < N_EDGES) atomicAdd(&cnt[col[i]], 1);
}

// per-block sums of 1024-element chunks (int4 per thread, coalesced)
__launch_bounds__(256)
__global__ void k_scan1(const int* __restrict__ cnt, int* __restrict__ bsum) {
    const int t = threadIdx.x, b = blockIdx.x;
    const int idx = b * 1024 + t * 4;
    int4 v = make_int4(0, 0, 0, 0);
    if (idx < N_NODES) v = *(const int4*)&cnt[idx];   // N_NODES % 4 == 0
    int s = v.x + v.y + v.z + v.w;
    #pragma unroll
    for (int d = 1; d < 64; d <<= 1) s += __shfl_xor(s, d, 64);
    __shared__ int ws[4];
    if ((t & 63) == 0) ws[t >> 6] = s;
    __syncthreads();
    if (t == 0) bsum[b] = ws[0] + ws[1] + ws[2] + ws[3];
}

// one wave scans the 49 block sums -> exclusive block offsets
__global__ void k_scan2(const int* __restrict__ bsum, int* __restrict__ boff) {
    const int t = threadIdx.x;   // 64
    int v = (t < NBLK_SCAN) ? bsum[t] : 0;
    int inc = wave_incl_scan(v, t);
    if (t < NBLK_SCAN) boff[t] = inc - v;
}

// in-block exclusive scan + block offset -> row_ptr; fused dinv/cursor init
__launch_bounds__(256)
__global__ void k_scan3(const int* __restrict__ cnt, const int* __restrict__ boff,
                        int* __restrict__ row_ptr, float* __restrict__ dinv,
                        int* __restrict__ cursor) {
    const int t = threadIdx.x, b = blockIdx.x;
    const int lane = t & 63, wv = t >> 6;
    const int idx = b * 1024 + t * 4;
    int4 v = make_int4(0, 0, 0, 0);
    if (idx < N_NODES) v = *(const int4*)&cnt[idx];
    int s = v.x + v.y + v.z + v.w;
    int isc = wave_incl_scan(s, lane);
    __shared__ int wsum[4];
    if (lane == 63) wsum[wv] = isc;
    __syncthreads();
    int off = boff[b];
    #pragma unroll
    for (int i = 0; i < 4; ++i)
        if (i < wv) off += wsum[i];
    int p0 = off + isc - s;
    int p1 = p0 + v.x;
    int p2 = p1 + v.y;
    int p3 = p2 + v.z;
    if (idx < N_NODES) {
        row_ptr[idx + 0] = p0; cursor[idx + 0] = p0; dinv[idx + 0] = rsqrtf(1.f + (float)v.x);
        row_ptr[idx + 1] = p1; cursor[idx + 1] = p1; dinv[idx + 1] = rsqrtf(1.f + (float)v.y);
        row_ptr[idx + 2] = p2; cursor[idx + 2] = p2; dinv[idx + 2] = rsqrtf(1.f + (float)v.z);
        row_ptr[idx + 3] = p3; cursor[idx + 3] = p3; dinv[idx + 3] = rsqrtf(1.f + (float)v.w);
    }
    if (b == 0 && t == 0) row_ptr[N_NODES] = N_EDGES;
}

__global__ void k_fill(const int* __restrict__ row, const int* __restrict__ col,
                       int* __restrict__ cursor, int* __restrict__ csr_src) {
    int i = blockIdx.x * 256 + threadIdx.x;
    if (i < N_EDGES) {
        int pos = atomicAdd(&cursor[col[i]], 1);
        csr_src[pos] = row[i];
    }
}

// ============ W transpose + bf16 convert: Wt[n][k] = bf16(W[k][n]) ============
__global__ void k_wt(const float* __restrict__ W, unsigned short* __restrict__ Wt) {
    int k = blockIdx.x;      // 512
    int n = threadIdx.x;     // 256
    Wt[(size_t)n * D_IN + k] = bf16b(W[(size_t)k * D_OUT + n]);
}

// ============ MFMA GEMM: yb = bf16((x @ W) * dinv[row]) ============
__launch_bounds__(256)
__global__ void k_gemm(const float* __restrict__ A,            // [N_NODES, 512] fp32
                       const unsigned short* __restrict__ Wt,  // [256, 512] bf16
                       const float* __restrict__ dinv,
                       unsigned short* __restrict__ yb)        // [N_NODES, 256] bf16
{
    __shared__ __align__(16) unsigned short As[128 * 64];   // [m][k], swizzled
    __shared__ __align__(16) unsigned short Bs[128 * 64];   // [n][k], swizzled

    const int t  = threadIdx.x;
    const int nt = blockIdx.x & 1;
    const int mt = blockIdx.x >> 1;
    const int m0 = mt * 128;
    const int n0 = nt * 128;

    const int w  = t >> 6;
    const int l  = t & 63;
    const int wm = (w >> 1) * 64;
    const int wn = (w & 1) * 64;
    const int lr = l & 15;
    const int lk = l >> 4;

    const int sr   = t >> 3;
    const int skg  = t & 7;
    const int swz  = (sr & 7) << 4;
    const int aswz = (lr & 7) << 4;

    f32x4 acc[4][4] = {};

    for (int kk = 0; kk < D_IN; kk += 64) {
        #pragma unroll
        for (int i = 0; i < 4; ++i) {
            int m   = i * 32 + sr;
            int row = m0 + m;
            float4 v0 = make_float4(0.f,0.f,0.f,0.f), v1 = v0;
            if (row < N_NODES) {
                const float* src = &A[(size_t)row * D_IN + kk + skg * 8];
                v0 = *(const float4*)src;
                v1 = *(const float4*)(src + 4);
            }
            union { uint4 q; unsigned short h[8]; } pk;
            pk.h[0] = bf16b(v0.x); pk.h[1] = bf16b(v0.y);
            pk.h[2] = bf16b(v0.z); pk.h[3] = bf16b(v0.w);
            pk.h[4] = bf16b(v1.x); pk.h[5] = bf16b(v1.y);
            pk.h[6] = bf16b(v1.z); pk.h[7] = bf16b(v1.w);
            *(uint4*)((char*)As + ((m * 128 + skg * 16) ^ swz)) = pk.q;
        }
        #pragma unroll
        for (int i = 0; i < 4; ++i) {
            int n = i * 32 + sr;
            uint4 q = *(const uint4*)&Wt[(size_t)(n0 + n) * D_IN + kk + skg * 8];
            *(uint4*)((char*)Bs + ((n * 128 + skg * 16) ^ swz)) = q;
        }
        __syncthreads();

        #pragma unroll
        for (int ks = 0; ks < 2; ++ks) {
            const int kb = (ks * 64 + lk * 16) ^ aswz;
            s8v af[4], bfr[4];
            #pragma unroll
            for (int f = 0; f < 4; ++f)
                af[f]  = *(const s8v*)((const char*)As + ((wm + f * 16 + lr) * 128 + kb));
            #pragma unroll
            for (int f = 0; f < 4; ++f)
                bfr[f] = *(const s8v*)((const char*)Bs + ((wn + f * 16 + lr) * 128 + kb));
            #pragma unroll
            for (int fm = 0; fm < 4; ++fm)
                #pragma unroll
                for (int fn = 0; fn < 4; ++fn)
                    acc[fm][fn] = __builtin_amdgcn_mfma_f32_16x16x32_bf16(
                        af[fm], bfr[fn], acc[fm][fn], 0, 0, 0);
        }
        __syncthreads();
    }

    #pragma unroll
    for (int fm = 0; fm < 4; ++fm) {
        #pragma unroll
        for (int j = 0; j < 4; ++j) {
            int row = m0 + wm + fm * 16 + lk * 4 + j;
            if (row < N_NODES) {
                float s = dinv[row];
                #pragma unroll
                for (int fn = 0; fn < 4; ++fn) {
                    int col = n0 + wn + fn * 16 + lr;
                    yb[(size_t)row * D_OUT + col] = bf16b(acc[fm][fn][j] * s);
                }
            }
        }
    }
}

// ============ gather: out[c] = relu(dinv[c]*(yb[c] + sum yb[src]) + b) ============
__device__ __forceinline__ void add8(float* acc, uint4 q) {
    unsigned x;
    x = q.x; acc[0] += __uint_as_float(x << 16); acc[1] += __uint_as_float(x & 0xffff0000u);
    x = q.y; acc[2] += __uint_as_float(x << 16); acc[3] += __uint_as_float(x & 0xffff0000u);
    x = q.z; acc[4] += __uint_as_float(x << 16); acc[5] += __uint_as_float(x & 0xffff0000u);
    x = q.w; acc[6] += __uint_as_float(x << 16); acc[7] += __uint_as_float(x & 0xffff0000u);
}

__launch_bounds__(256)
__global__ void k_gather(const int* __restrict__ row_ptr, const int* __restrict__ csr_src,
                         const unsigned short* __restrict__ yb, const float* __restrict__ dinv,
                         const float* __restrict__ bias, float* __restrict__ out)
{
    const int c  = blockIdx.x * 4 + (threadIdx.x >> 6);
    const int l  = threadIdx.x & 63;
    const int eg = l >> 5;
    const int cs = l & 31;
    const size_t colb = (size_t)cs * 8;

    float acc[8] = {0.f,0.f,0.f,0.f,0.f,0.f,0.f,0.f};

    const int s = row_ptr[c];
    const int e = row_ptr[c + 1];

    int i = s + eg;
    while (i + 14 < e) {
        int r[8];
        #pragma unroll
        for (int u = 0; u < 8; ++u) r[u] = csr_src[i + 2 * u];
        uint4 v[8];
        #pragma unroll
        for (int u = 0; u < 8; ++u) v[u] = *(const uint4*)&yb[(size_t)r[u] * D_OUT + colb];
        #pragma unroll
        for (int u = 0; u < 8; ++u) add8(acc, v[u]);
        i += 16;
    }
    if (i + 6 < e) {
        int r[4];
        #pragma unroll
        for (int u = 0; u < 4; ++u) r[u] = csr_src[i + 2 * u];
        uint4 v[4];
        #pragma unroll
        for (int u = 0; u < 4; ++u) v[u] = *(const uint4*)&yb[(size_t)r[u] * D_OUT + colb];
        #pragma unroll
        for (int u = 0; u < 4; ++u) add8(acc, v[u]);
        i += 8;
    }
    while (i < e) {
        int r = csr_src[i];
        uint4 v = *(const uint4*)&yb[(size_t)r * D_OUT + colb];
        add8(acc, v);
        i += 2;
    }

    #pragma unroll
    for (int u = 0; u < 8; ++u) acc[u] += __shfl_xor(acc[u], 32, 64);

    uint4 sv = *(const uint4*)&yb[(size_t)c * D_OUT + colb];
    add8(acc, sv);

    if (eg == 0) {
        const float sc = dinv[c];
        float4 b0 = *(const float4*)&bias[colb];
        float4 b1 = *(const float4*)&bias[colb + 4];
        float4 o0, o1;
        o0.x = fmaxf(fmaf(acc[0], sc, b0.x), 0.f);
        o0.y = fmaxf(fmaf(acc[1], sc, b0.y), 0.f);
        o0.z = fmaxf(fmaf(acc[2], sc, b0.z), 0.f);
        o0.w = fmaxf(fmaf(acc[3], sc, b0.w), 0.f);
        o1.x = fmaxf(fmaf(acc[4], sc, b1.x), 0.f);
        o1.y = fmaxf(fmaf(acc[5], sc, b1.y), 0.f);
        o1.z = fmaxf(fmaf(acc[6], sc, b1.z), 0.f);
        o1.w = fmaxf(fmaf(acc[7], sc, b1.w), 0.f);
        float* dst = &out[(size_t)c * D_OUT + colb];
        *(float4*)dst       = o0;
        *(float4*)(dst + 4) = o1;
    }
}

extern "C" void kernel_launch(void* const* d_in, const int* in_sizes, int n_in,
                              void* d_out, int out_size, void* d_ws, size_t ws_size,
                              hipStream_t stream) {
    const float* x   = (const float*)d_in[0];
    const int*   ei  = (const int*)d_in[1];
    const float* W   = (const float*)d_in[2];
    const float* b   = (const float*)d_in[3];
    float*       out = (float*)d_out;

    const int* row = ei;
    const int* col = ei + N_EDGES;

    char* p = (char*)d_ws;
    unsigned short* yb = (unsigned short*)p;  p += (size_t)N_NODES * D_OUT * 2;   // 25.6 MB
    unsigned short* Wt = (unsigned short*)p;  p += (size_t)D_OUT * D_IN * 2;      // 256 KB
    int*   csr_src = (int*)p;                 p += (size_t)N_EDGES * 4;           // 3.2 MB
    int*   cnt     = (int*)p;                 p += (size_t)N_NODES * 4;           // 16B-aligned here
    int*   row_ptr = (int*)p;                 p += (size_t)(N_NODES + 4) * 4;
    int*   cursor  = (int*)p;                 p += (size_t)N_NODES * 4;
    float* dinv    = (float*)p;               p += (size_t)N_NODES * 4;
    int*   bsum    = (int*)p;                 p += (size_t)NBLK_SCAN * 4;
    int*   boff    = (int*)p;                 p += (size_t)NBLK_SCAN * 4;

    hipMemsetAsync(cnt, 0, (size_t)N_NODES * sizeof(int), stream);
    k_count<<<(N_EDGES + 255) / 256, 256, 0, stream>>>(col, cnt);
    k_scan1<<<NBLK_SCAN, 256, 0, stream>>>(cnt, bsum);
    k_scan2<<<1, 64, 0, stream>>>(bsum, boff);
    k_scan3<<<NBLK_SCAN, 256, 0, stream>>>(cnt, boff, row_ptr, dinv, cursor);
    k_fill <<<(N_EDGES + 255) / 256, 256, 0, stream>>>(row, col, cursor, csr_src);
    k_wt   <<<D_IN, D_OUT, 0, stream>>>(W, Wt);

    k_gemm<<<((N_NODES + 127) / 128) * 2, 256, 0, stream>>>(x, Wt, dinv, yb);

    k_gather<<<N_NODES / 4, 256, 0, stream>>>(row_ptr, csr_src, yb, dinv, b, out);
}